// Round 8
// baseline (1370.919 us; speedup 1.0000x reference)
//
#include <hip/hip_runtime.h>
#include <hip/hip_bf16.h>

// RGCN regression: N=50000, E=800000, R=8, C=H=128.
// Round 8: fused agg+GEMM v2 — EDGE-PARALLEL gather (R7 failed on serialized
// per-segment load chains: MfmaUtil 5.5%, VALU 22.6%, nothing busy).
//  - edges re-sorted by (rel, dst) -> per (block,rel) the edge range is contiguous
//  - gather: 4 threads/edge, independent 64B loads, ds_add_f32 scatter into a
//    rotated-layout 32x128 f32 LDS accumulator (no dependent chains at all)
//  - then scale(1/cnt) -> bf16 -> swizzled A-tile -> MFMA (proven R7 compute)
//  - LDS 56KB (A 8K | B 32K | accum 16K) -> 2 blocks/CU; M-tile 32, 1563 blocks
// Sort prep reshaped: coarse bucket (rel<<8)|(dst>>8) = 2048 buckets; fine sort
// emits off2[(r<<16)|dst] and srcs2 = packed (dlow<<16)|src.

constexpr int NN = 50000;
constexpr int EE = 800000;
constexpr int NCB2 = 2048;            // coarse buckets: (rel<<8)|(dst>>8)
constexpr int EPB = 8192;             // edges per partition block
constexpr int PBLK = (EE + EPB - 1) / EPB;   // 98

typedef __attribute__((ext_vector_type(8))) short bf16x8;
typedef __attribute__((ext_vector_type(16))) float f32x16;
typedef __attribute__((address_space(3))) uint32_t lds_u32;
typedef __attribute__((address_space(1))) const uint32_t glb_u32;

static __device__ __forceinline__ ushort f2bf(float f) {
    uint u = __float_as_uint(f);
    uint r = (u + 0x7fffu + ((u >> 16) & 1u)) >> 16;   // RTNE
    return (ushort)r;
}
static __device__ __forceinline__ float bflo(uint v) { return __uint_as_float(v << 16); }
static __device__ __forceinline__ float bfhi(uint v) { return __uint_as_float(v & 0xffff0000u); }

static __device__ __forceinline__ void stage16(const void* g, void* lds) {
    __builtin_amdgcn_global_load_lds((glb_u32*)g, (lds_u32*)lds, 16, 0, 0);
}

// ---------------- P1: coarse histogram over (rel<<8)|(dst>>8) ----------------
__global__ __launch_bounds__(1024) void chist_kernel(const int* __restrict__ dst,
                                                     const int* __restrict__ et,
                                                     int* __restrict__ ghist) {
    __shared__ int h[NCB2];
    const int t = threadIdx.x;
    for (int i = t; i < NCB2; i += 1024) h[i] = 0;
    __syncthreads();
    const int e0 = blockIdx.x * EPB + t;
#pragma unroll
    for (int jj = 0; jj < 8; ++jj) {
        const int e = e0 + jj * 1024;
        if (e < EE) atomicAdd(&h[(et[e] << 8) | (dst[e] >> 8)], 1);
    }
    __syncthreads();
    for (int i = t; i < NCB2; i += 1024)
        if (h[i]) atomicAdd(&ghist[i], h[i]);
}

// ---------------- P2: exclusive scan over 2048 coarse totals ----------------
__global__ __launch_bounds__(1024) void cscan_kernel(const int* __restrict__ ghist,
                                                     int* __restrict__ gstart,
                                                     int* __restrict__ gcur) {
    __shared__ int sm[1024];
    const int t = threadIdx.x;
    const int v0 = ghist[2 * t], v1 = ghist[2 * t + 1];
    sm[t] = v0 + v1;
    __syncthreads();
    for (int d = 1; d < 1024; d <<= 1) {
        int u = (t >= d) ? sm[t - d] : 0;
        __syncthreads();
        sm[t] += u;
        __syncthreads();
    }
    const int base = sm[t] - (v0 + v1);
    gstart[2 * t] = base;       gcur[2 * t] = base;
    gstart[2 * t + 1] = base + v0; gcur[2 * t + 1] = base + v0;
    if (t == 1023) gstart[NCB2] = sm[1023];   // == EE
}

// ---------------- P3: coarse partition; packed = (dlow<<16)|src ----------------
__global__ __launch_bounds__(1024) void cpart_kernel(const int* __restrict__ src,
                                                     const int* __restrict__ dst,
                                                     const int* __restrict__ et,
                                                     int* __restrict__ gcur,
                                                     uint* __restrict__ packed) {
    __shared__ int h[NCB2];
    const int t = threadIdx.x;
    for (int i = t; i < NCB2; i += 1024) h[i] = 0;
    __syncthreads();
    const int e0 = blockIdx.x * EPB + t;
    int myb[8]; uint mydat[8];
#pragma unroll
    for (int jj = 0; jj < 8; ++jj) {
        const int e = e0 + jj * 1024;
        if (e < EE) {
            const int d = dst[e];
            myb[jj] = (et[e] << 8) | (d >> 8);
            mydat[jj] = (uint)src[e] | ((uint)(d & 255) << 16);
            atomicAdd(&h[myb[jj]], 1);
        } else myb[jj] = -1;
    }
    __syncthreads();
    for (int i = t; i < NCB2; i += 1024)
        h[i] = h[i] ? atomicAdd(&gcur[i], h[i]) : 0;   // h becomes running cursor
    __syncthreads();
#pragma unroll
    for (int jj = 0; jj < 8; ++jj) {
        if (myb[jj] >= 0) {
            const int pos = atomicAdd(&h[myb[jj]], 1);
            packed[pos] = mydat[jj];
        }
    }
}

// ---------------- P4: per-bucket fine sort by dlow -> off2[] + srcs2[] ----------------
__global__ __launch_bounds__(256) void fsort_kernel(const int* __restrict__ gstart,
                                                    const uint* __restrict__ packed,
                                                    int* __restrict__ off2,
                                                    uint* __restrict__ srcs2) {
    __shared__ int hist[256], sm[256], scn[256];
    const int b = blockIdx.x;
    const int t = threadIdx.x;
    const int s = gstart[b], e = gstart[b + 1];
    hist[t] = 0;
    __syncthreads();
    for (int i = s + t; i < e; i += 256)
        atomicAdd(&hist[(packed[i] >> 16) & 255], 1);
    __syncthreads();
    const int v = hist[t];
    sm[t] = v;
    __syncthreads();
    for (int d = 1; d < 256; d <<= 1) {
        int u = (t >= d) ? sm[t - d] : 0;
        __syncthreads();
        sm[t] += u;
        __syncthreads();
    }
    const int pos0 = s + sm[t] - v;
    off2[(b << 8) + t] = pos0;         // off2[(r<<16)|dst] boundaries
    scn[t] = pos0;
    __syncthreads();
    for (int i = s + t; i < e; i += 256) {
        const uint w = packed[i];
        const int p = atomicAdd(&scn[(w >> 16) & 255], 1);
        srcs2[p] = w;
    }
}

// ---------------- x fp32 -> bf16 ----------------
__global__ __launch_bounds__(256) void cvt_x_kernel(const float* __restrict__ x,
                                                    ushort* __restrict__ xb) {
    const int tid = blockIdx.x * blockDim.x + threadIdx.x;
    const size_t i = (size_t)tid * 8;
    const float4 v0 = *reinterpret_cast<const float4*>(x + i);
    const float4 v1 = *reinterpret_cast<const float4*>(x + i + 4);
    uint4 o;
    o.x = (uint)f2bf(v0.x) | ((uint)f2bf(v0.y) << 16);
    o.y = (uint)f2bf(v0.z) | ((uint)f2bf(v0.w) << 16);
    o.z = (uint)f2bf(v1.x) | ((uint)f2bf(v1.y) << 16);
    o.w = (uint)f2bf(v1.z) | ((uint)f2bf(v1.w) << 16);
    *reinterpret_cast<uint4*>(xb + i) = o;
}

// ---------------- weights -> Bt[n][k] bf16, k = [root(128) | W(1024)] ----------------
__global__ __launch_bounds__(256) void prep_w_kernel(const float* __restrict__ root1,
                                                     const float* __restrict__ W1,
                                                     const float* __restrict__ root2,
                                                     const float* __restrict__ W2,
                                                     ushort* __restrict__ Bt1,
                                                     ushort* __restrict__ Bt2) {
    const float* root = blockIdx.y ? root2 : root1;
    const float* W    = blockIdx.y ? W2 : W1;
    ushort* Bt        = blockIdx.y ? Bt2 : Bt1;
    const int n = blockIdx.x;
    for (int k = threadIdx.x; k < 1152; k += 256) {
        float v = (k < 128) ? root[(size_t)k * 128 + n]
                            : W[(size_t)(k - 128) * 128 + n];
        Bt[(size_t)n * 1152 + k] = f2bf(v);
    }
}

// ---------------- FUSED agg+GEMM v2: h = relu(bias + [xb | mean_r] @ Bt^T) ----------------
// Block: 256 thr = 4 waves, tile 32(M) x 128(N), BK=128, mfma 32x32x16.
// LDS: A 32x256B (8K, chunk^(row&7)) | B 128x256B (32K, same) | accum 32x128 f32 (16K,
// rotated: dword idx = local*128 + ((f + local*4)&127) -> ds_add banks spread).
__global__ __launch_bounds__(256) void gemm_fused(const ushort* __restrict__ feat,
                                                  const int* __restrict__ off2,
                                                  const uint* __restrict__ srcs2,
                                                  const ushort* __restrict__ Bt,
                                                  const float* __restrict__ bias,
                                                  ushort* __restrict__ hout) {
    __shared__ __align__(16) uint8_t smem[57344];   // A[0,8K) B[8K,40K) accum[40K,56K)
    float* accF = (float*)(smem + 40960);
    const int t = threadIdx.x;
    const int lane = t & 63;
    const int w = t >> 6;
    const int n0 = blockIdx.x * 32;
    const int l31 = lane & 31;
    const int lhalf = lane >> 5;

    f32x16 acc;
#pragma unroll
    for (int k = 0; k < 16; ++k) acc[k] = 0.f;

    // fragment read constants
    const int aoff = l31 * 256, aswz = (l31 & 7) << 4;
    const int nB = w * 32 + l31;
    const int boff = 8192 + nB * 256, bswz = (nB & 7) << 4;
    const int ckb = lhalf << 4;
    // staging lane mapping
    const int srow = lane >> 4, schunk = lane & 15;

    const uint8_t* feat8 = (const uint8_t*)feat;
    const uint8_t* Bt8   = (const uint8_t*)Bt;

    auto STAGE_B = [&](int kt) {                     // 8 instrs/wave, 32 rows
#pragma unroll
        for (int jj = 0; jj < 8; ++jj) {
            const int n = w * 32 + jj * 4 + srow;
            stage16(Bt8 + (size_t)n * 2304 + kt * 256 + ((schunk ^ (n & 7)) << 4),
                    smem + 8192 + (w * 32 + jj * 4) * 256);
        }
    };
    auto STAGE_A0 = [&]() {                          // 2 instrs/wave, 8 rows
#pragma unroll
        for (int jj = 0; jj < 2; ++jj) {
            const int lr = w * 8 + jj * 4 + srow;
            const int gr = min(n0 + lr, NN - 1);
            stage16(feat8 + (size_t)gr * 256 + ((schunk ^ (lr & 7)) << 4),
                    smem + (w * 8 + jj * 4) * 256);
        }
    };
    auto COMPUTE = [&]() {
#pragma unroll
        for (int kb = 0; kb < 8; ++kb) {
            const int cb = kb * 32 + ckb;
            const bf16x8 af = *reinterpret_cast<const bf16x8*>(smem + aoff + (cb ^ aswz));
            const bf16x8 bf = *reinterpret_cast<const bf16x8*>(smem + boff + (cb ^ bswz));
            acc = __builtin_amdgcn_mfma_f32_32x32x16_bf16(af, bf, acc, 0, 0, 0);
        }
    };

    // zero accum (4096 dwords)
    {
        int* accI = (int*)accF;
#pragma unroll
        for (int k = 0; k < 16; ++k) accI[t * 16 + k] = 0;
    }
    STAGE_A0();
    STAGE_B(0);
    __syncthreads();                  // vmcnt+lgkm drain: A,B,zeros ready
    COMPUTE();                        // tile 0 (root term)

    const int sub = t & 3;            // gather: 4 threads/edge, 64B each
    const int cvloc = t >> 3, cvj = t & 7;   // convert: 8 threads/node

#pragma unroll 1
    for (int r = 0; r < 8; ++r) {
        __syncthreads();              // tile r's B/A reads done
        STAGE_B(r + 1);               // async under gather
        // ---- edge-parallel gather with LDS atomic scatter ----
        const int s = off2[(r << 16) | n0];
        const int e = off2[(r << 16) | (n0 + 32)];
        for (int q = s + (t >> 2); q < e; q += 64) {
            const uint wd = srcs2[q];
            const int fsrc = (int)(wd & 0xFFFF);
            const int local = (int)((wd >> 16) & 31);
            const uint4* rp = reinterpret_cast<const uint4*>(
                feat8 + (size_t)fsrc * 256 + (sub << 6));
            const uint4 q0 = rp[0], q1 = rp[1], q2 = rp[2], q3 = rp[3];
            const uint u[16] = { q0.x,q0.y,q0.z,q0.w, q1.x,q1.y,q1.z,q1.w,
                                 q2.x,q2.y,q2.z,q2.w, q3.x,q3.y,q3.z,q3.w };
            const int a0 = sub * 32 + local * 4;
            float* arow = accF + local * 128;
#pragma unroll
            for (int m = 0; m < 16; ++m) {
                const int fm = (a0 + 2 * m) & 127;     // even; fm+1 safe
                atomicAdd(&arow[fm],     bflo(u[m]));
                atomicAdd(&arow[fm + 1], bfhi(u[m]));
            }
        }
        __syncthreads();              // ds_adds visible + B staged
        // ---- convert: accum -> mean -> bf16 A-tile; re-zero accum ----
        {
            const int gs = off2[(r << 16) | (n0 + cvloc)];
            const int ge = off2[(r << 16) | (n0 + cvloc + 1)];
            const float inv = 1.0f / (float)max(ge - gs, 1);
            float* arow = accF + cvloc * 128;
            uint o[8];
#pragma unroll
            for (int k = 0; k < 8; ++k) {
                const int f0 = (cvj * 16 + 2 * k + cvloc * 4) & 127;   // even
                const float v0 = arow[f0];     arow[f0] = 0.f;
                const float v1 = arow[f0 + 1]; arow[f0 + 1] = 0.f;
                o[k] = (uint)f2bf(v0 * inv) | ((uint)f2bf(v1 * inv) << 16);
            }
            const int c0 = (2 * cvj) ^ (cvloc & 7);
            const int c1 = (2 * cvj + 1) ^ (cvloc & 7);
            *reinterpret_cast<uint4*>(smem + cvloc * 256 + c0 * 16) =
                make_uint4(o[0], o[1], o[2], o[3]);
            *reinterpret_cast<uint4*>(smem + cvloc * 256 + c1 * 16) =
                make_uint4(o[4], o[5], o[6], o[7]);
        }
        __syncthreads();              // A written, accum zeroed
        COMPUTE();                    // tile r+1
    }

    // epilogue: 32x32 C/D: col = lane&31 (B side), row = (reg&3)+8*(reg>>2)+4*lhalf
    const int col = w * 32 + l31;
    const float bv = bias[col];
#pragma unroll
    for (int reg = 0; reg < 16; ++reg) {
        const int row = n0 + 4 * lhalf + (reg & 3) + 8 * (reg >> 2);
        if (row < NN) {
            const float v = fmaxf(acc[reg] + bv, 0.f);
            hout[(size_t)row * 128 + col] = f2bf(v);
        }
    }
}

// ---------------- head: out[n] = h2[n] . Wout + bout ----------------
__global__ __launch_bounds__(256) void out_kernel(const ushort* __restrict__ h2,
                                                  const float* __restrict__ Wout,
                                                  const float* __restrict__ bout,
                                                  float* __restrict__ outp) {
    const int wid = (blockIdx.x * blockDim.x + threadIdx.x) >> 6;
    if (wid >= NN) return;
    const int lane = threadIdx.x & 63;
    const uint v = *reinterpret_cast<const uint*>(h2 + (size_t)wid * 128 + (lane << 1));
    const float2 ww = *reinterpret_cast<const float2*>(Wout + (lane << 1));
    float s = fmaf(bflo(v), ww.x, bfhi(v) * ww.y);
#pragma unroll
    for (int d = 32; d > 0; d >>= 1) s += __shfl_down(s, d, 64);
    if (lane == 0) outp[wid] = s + bout[0];
}

extern "C" void kernel_launch(void* const* d_in, const int* in_sizes, int n_in,
                              void* d_out, int out_size, void* d_ws, size_t ws_size,
                              hipStream_t stream) {
    const float* x     = (const float*)d_in[0];
    const int*   eidx  = (const int*)  d_in[1];
    const int*   etype = (const int*)  d_in[2];
    const float* W1    = (const float*)d_in[3];
    const float* root1 = (const float*)d_in[4];
    const float* b1    = (const float*)d_in[5];
    const float* W2    = (const float*)d_in[6];
    const float* root2 = (const float*)d_in[7];
    const float* b2    = (const float*)d_in[8];
    const float* Wout  = (const float*)d_in[9];
    const float* bout  = (const float*)d_in[10];
    float* out = (float*)d_out;

    const int* src = eidx;
    const int* dst = eidx + EE;

    char* ws = (char*)d_ws;
    size_t pos = 0;
    auto take = [&](size_t bytes) {
        char* p = ws + pos;
        pos = (pos + bytes + 255) & ~(size_t)255;
        return p;
    };
    int*    ghist  = (int*)   take((size_t)NCB2 * 4);
    int*    gstart = (int*)   take((size_t)(NCB2 + 1) * 4);
    int*    gcur   = (int*)   take((size_t)NCB2 * 4);
    uint*   packed = (uint*)  take((size_t)EE * 4);
    int*    off2   = (int*)   take(((size_t)(8 << 16) + 1) * 4);   // [(r<<16)|dst]
    uint*   srcs2  = (uint*)  take((size_t)EE * 4);
    ushort* xb     = (ushort*)take((size_t)NN * 128 * 2);
    ushort* h1     = (ushort*)take((size_t)NN * 128 * 2);
    ushort* h2     = (ushort*)take((size_t)NN * 128 * 2);
    ushort* Bt1    = (ushort*)take((size_t)128 * 1152 * 2);
    ushort* Bt2    = (ushort*)take((size_t)128 * 1152 * 2);
    (void)ws_size; (void)n_in; (void)in_sizes; (void)out_size;

    const int wblocks = (NN + 3) / 4;               // 12500 (head)
    const int gblocks = (NN + 31) / 32;             // 1563 fused tiles

    hipMemsetAsync(ghist, 0, (size_t)NCB2 * 4, stream);
    chist_kernel<<<PBLK, 1024, 0, stream>>>(dst, etype, ghist);
    cscan_kernel<<<1, 1024, 0, stream>>>(ghist, gstart, gcur);
    cpart_kernel<<<PBLK, 1024, 0, stream>>>(src, dst, etype, gcur, packed);
    fsort_kernel<<<NCB2, 256, 0, stream>>>(gstart, packed, off2, srcs2);
    prep_w_kernel<<<dim3(128, 2), 256, 0, stream>>>(root1, W1, root2, W2, Bt1, Bt2);
    cvt_x_kernel <<<3125, 256, 0, stream>>>(x, xb);

    // layer 1 (fused agg+gemm)
    gemm_fused<<<gblocks, 256, 0, stream>>>(xb, off2, srcs2, Bt1, b1, h1);
    // layer 2
    gemm_fused<<<gblocks, 256, 0, stream>>>(h1, off2, srcs2, Bt2, b2, h2);
    // head
    out_kernel<<<wblocks, 256, 0, stream>>>(h2, Wout, bout, out);
}

// Round 9
// 219.390 us; speedup vs baseline: 6.2488x; 6.2488x over previous
//
#include <hip/hip_runtime.h>
#include <hip/hip_bf16.h>

// RGCN regression: N=50000, E=800000, R=8, C=H=128.
// Round 9: REVERT to R6 structure (217us known-good; R7/R8 fusion attempts were
// latency-serialized / LDS-atomic-bound, 253/1371us). Single change vs R6:
// agg segment walk unrolled x2 (two independent accumulator banks, paired src
// prefetch) -> half the iterations, 4 row-loads in flight, less loop overhead.
//  1) 2-level MSD partition sort by (dst,rel)  [R6]
//  2) cvt x -> bf16; weights -> Bt[n][k] bf16  [R6]
//  3) per layer: wave-per-node agg, 8 rel-groups x 8 lanes, UNROLL 2  [new]
//  4) per layer: MFMA GEMM 64x128 tile, BK=64, gload_lds dbuf  [R6]
//  5) head dot  [R6]

constexpr int NN = 50000;
constexpr int EE = 800000;
constexpr int NB = NN * 8;            // 400000 (dst,rel) buckets
constexpr int NCB = (NN + 255) >> 8;  // 196 coarse buckets
constexpr int EPB = 8192;             // edges per partition block
constexpr int PBLK = (EE + EPB - 1) / EPB;   // 98
constexpr int NSB = 2048;             // sub-buckets per coarse bucket

typedef __attribute__((ext_vector_type(8))) short bf16x8;
typedef __attribute__((ext_vector_type(16))) float f32x16;
typedef __attribute__((address_space(3))) uint32_t lds_u32;
typedef __attribute__((address_space(1))) const uint32_t glb_u32;

static __device__ __forceinline__ ushort f2bf(float f) {
    uint u = __float_as_uint(f);
    uint r = (u + 0x7fffu + ((u >> 16) & 1u)) >> 16;   // RTNE
    return (ushort)r;
}
static __device__ __forceinline__ float bflo(uint v) { return __uint_as_float(v << 16); }
static __device__ __forceinline__ float bfhi(uint v) { return __uint_as_float(v & 0xffff0000u); }

static __device__ __forceinline__ void stage16(const void* g, void* lds) {
    __builtin_amdgcn_global_load_lds((glb_u32*)g, (lds_u32*)lds, 16, 0, 0);
}

// ---------------- P1: coarse histogram (dst>>8), LDS-aggregated ----------------
__global__ __launch_bounds__(1024) void chist_kernel(const int* __restrict__ dst,
                                                     int* __restrict__ ghist) {
    __shared__ int h[NCB];
    const int t = threadIdx.x;
    for (int i = t; i < NCB; i += 1024) h[i] = 0;
    __syncthreads();
    const int e0 = blockIdx.x * EPB + t;
#pragma unroll
    for (int jj = 0; jj < 8; ++jj) {
        const int e = e0 + jj * 1024;
        if (e < EE) atomicAdd(&h[dst[e] >> 8], 1);
    }
    __syncthreads();
    for (int i = t; i < NCB; i += 1024)
        if (h[i]) atomicAdd(&ghist[i], h[i]);
}

// ---------------- P2: scan 196 coarse totals ----------------
__global__ __launch_bounds__(256) void cscan_kernel(const int* __restrict__ ghist,
                                                    int* __restrict__ gstart,
                                                    int* __restrict__ gcur) {
    __shared__ int sm[256];
    const int t = threadIdx.x;
    const int v = (t < NCB) ? ghist[t] : 0;
    sm[t] = v;
    __syncthreads();
    for (int d = 1; d < 256; d <<= 1) {
        int u = (t >= d) ? sm[t - d] : 0;
        __syncthreads();
        sm[t] += u;
        __syncthreads();
    }
    const int excl = sm[t] - v;
    if (t < NCB) { gstart[t] = excl; gcur[t] = excl; }
    if (t == NCB - 1) gstart[NCB] = excl + v;   // == EE
}

// ---------------- P3: coarse partition, block-reserved ranges ----------------
// packed = (dlow<<19) | (et<<16) | src
__global__ __launch_bounds__(1024) void cpart_kernel(const int* __restrict__ src,
                                                     const int* __restrict__ dst,
                                                     const int* __restrict__ et,
                                                     int* __restrict__ gcur,
                                                     uint* __restrict__ packed) {
    __shared__ int h[NCB];
    const int t = threadIdx.x;
    for (int i = t; i < NCB; i += 1024) h[i] = 0;
    __syncthreads();
    const int e0 = blockIdx.x * EPB + t;
    int myb[8]; uint mydat[8];
#pragma unroll
    for (int jj = 0; jj < 8; ++jj) {
        const int e = e0 + jj * 1024;
        if (e < EE) {
            const int d = dst[e];
            myb[jj] = d >> 8;
            mydat[jj] = (uint)src[e] | ((uint)et[e] << 16) | ((uint)(d & 255) << 19);
            atomicAdd(&h[myb[jj]], 1);
        } else myb[jj] = -1;
    }
    __syncthreads();
    for (int i = t; i < NCB; i += 1024)
        h[i] = h[i] ? atomicAdd(&gcur[i], h[i]) : 0;   // h becomes running cursor
    __syncthreads();
#pragma unroll
    for (int jj = 0; jj < 8; ++jj) {
        if (myb[jj] >= 0) {
            const int pos = atomicAdd(&h[myb[jj]], 1);
            packed[pos] = mydat[jj];
        }
    }
}

// ---------------- P4: per-coarse-bucket fine sort -> off[] + srcs[] ----------------
__global__ __launch_bounds__(1024) void fsort_kernel(const int* __restrict__ gstart,
                                                     const uint* __restrict__ packed,
                                                     int* __restrict__ off,
                                                     int* __restrict__ srcs) {
    __shared__ int hist[NSB];
    __shared__ int scn[NSB];
    __shared__ int h2[1024];
    const int b = blockIdx.x;
    const int t = threadIdx.x;
    const int s = gstart[b], e = gstart[b + 1];

    for (int i = t; i < NSB; i += 1024) hist[i] = 0;
    __syncthreads();
    for (int i = s + t; i < e; i += 1024)
        atomicAdd(&hist[(packed[i] >> 16) & 0x7FF], 1);
    __syncthreads();
    const int a0 = hist[2 * t], a1 = hist[2 * t + 1];
    h2[t] = a0 + a1;
    __syncthreads();
    for (int d = 1; d < 1024; d <<= 1) {
        int u = (t >= d) ? h2[t - d] : 0;
        __syncthreads();
        h2[t] += u;
        __syncthreads();
    }
    const int base = h2[t] - (a0 + a1);
    scn[2 * t] = base;
    scn[2 * t + 1] = base + a0;
    __syncthreads();
    const int gsubbase = b << 11;
    for (int i = t; i < NSB; i += 1024) {
        const int g = gsubbase + i;
        if (g < NB) off[g] = s + scn[i];
    }
    if (b == NCB - 1 && t == 0) off[NB] = EE;
    __syncthreads();
    for (int i = s + t; i < e; i += 1024) {
        const uint k = packed[i];
        const int pos = atomicAdd(&scn[(k >> 16) & 0x7FF], 1);
        srcs[s + pos] = (int)(k & 0xFFFF);
    }
}

// ---------------- x fp32 -> bf16 ----------------
__global__ __launch_bounds__(256) void cvt_x_kernel(const float* __restrict__ x,
                                                    ushort* __restrict__ xb) {
    const int tid = blockIdx.x * blockDim.x + threadIdx.x;
    const size_t i = (size_t)tid * 8;
    const float4 v0 = *reinterpret_cast<const float4*>(x + i);
    const float4 v1 = *reinterpret_cast<const float4*>(x + i + 4);
    uint4 o;
    o.x = (uint)f2bf(v0.x) | ((uint)f2bf(v0.y) << 16);
    o.y = (uint)f2bf(v0.z) | ((uint)f2bf(v0.w) << 16);
    o.z = (uint)f2bf(v1.x) | ((uint)f2bf(v1.y) << 16);
    o.w = (uint)f2bf(v1.z) | ((uint)f2bf(v1.w) << 16);
    *reinterpret_cast<uint4*>(xb + i) = o;
}

// ---------------- weights -> Bt[n][k] bf16, k = [root(128) | W(1024)] ----------------
__global__ __launch_bounds__(256) void prep_w_kernel(const float* __restrict__ root1,
                                                     const float* __restrict__ W1,
                                                     const float* __restrict__ root2,
                                                     const float* __restrict__ W2,
                                                     ushort* __restrict__ Bt1,
                                                     ushort* __restrict__ Bt2) {
    const float* root = blockIdx.y ? root2 : root1;
    const float* W    = blockIdx.y ? W2 : W1;
    ushort* Bt        = blockIdx.y ? Bt2 : Bt1;
    const int n = blockIdx.x;
    for (int k = threadIdx.x; k < 1152; k += 256) {
        float v = (k < 128) ? root[(size_t)k * 128 + n]
                            : W[(size_t)(k - 128) * 128 + n];
        Bt[(size_t)n * 1152 + k] = f2bf(v);
    }
}

// ---------------- aggregation: one wave per node, 8 segments parallel, UNROLL 2 ----
// lane = g*8 + j : group g handles relation g; lane j owns bytes 32j..32j+31 of
// the 256B row. Two edges per iteration with independent accumulator banks.
__global__ __launch_bounds__(256) void agg_kernel(const int* __restrict__ off,
                                                  const int* __restrict__ srcs,
                                                  const ushort* __restrict__ feat,
                                                  ushort* __restrict__ agg) {
    const int wid = (blockIdx.x * blockDim.x + threadIdx.x) >> 6;
    if (wid >= NN) return;
    const int lane = threadIdx.x & 63;
    const int g = lane >> 3;            // relation group 0..7
    const int j = lane & 7;             // 32B chunk within row

    const int s1 = off[wid * 8 + g + 1];
    int i = off[wid * 8 + g];
    const int cnt = s1 - i;

    float a[16], b[16];
#pragma unroll
    for (int k = 0; k < 16; ++k) { a[k] = 0.f; b[k] = 0.f; }

    int p0 = (i < s1)     ? srcs[i]     : 0;
    int p1 = (i + 1 < s1) ? srcs[i + 1] : 0;
    while (__any(i < s1)) {
        const int q0 = (i + 2 < s1) ? srcs[i + 2] : 0;   // prefetch next pair
        const int q1 = (i + 3 < s1) ? srcs[i + 3] : 0;
        if (i < s1) {
            const ushort* row = feat + (size_t)p0 * 128 + (j << 4);
            const uint4 v0 = reinterpret_cast<const uint4*>(row)[0];
            const uint4 v1 = reinterpret_cast<const uint4*>(row)[1];
            a[0] += bflo(v0.x);  a[1] += bfhi(v0.x);
            a[2] += bflo(v0.y);  a[3] += bfhi(v0.y);
            a[4] += bflo(v0.z);  a[5] += bfhi(v0.z);
            a[6] += bflo(v0.w);  a[7] += bfhi(v0.w);
            a[8] += bflo(v1.x);  a[9] += bfhi(v1.x);
            a[10] += bflo(v1.y); a[11] += bfhi(v1.y);
            a[12] += bflo(v1.z); a[13] += bfhi(v1.z);
            a[14] += bflo(v1.w); a[15] += bfhi(v1.w);
        }
        if (i + 1 < s1) {
            const ushort* row = feat + (size_t)p1 * 128 + (j << 4);
            const uint4 v0 = reinterpret_cast<const uint4*>(row)[0];
            const uint4 v1 = reinterpret_cast<const uint4*>(row)[1];
            b[0] += bflo(v0.x);  b[1] += bfhi(v0.x);
            b[2] += bflo(v0.y);  b[3] += bfhi(v0.y);
            b[4] += bflo(v0.z);  b[5] += bfhi(v0.z);
            b[6] += bflo(v0.w);  b[7] += bfhi(v0.w);
            b[8] += bflo(v1.x);  b[9] += bfhi(v1.x);
            b[10] += bflo(v1.y); b[11] += bfhi(v1.y);
            b[12] += bflo(v1.z); b[13] += bfhi(v1.z);
            b[14] += bflo(v1.w); b[15] += bfhi(v1.w);
        }
        p0 = q0; p1 = q1;
        i += 2;
    }

    const float inv = 1.0f / (float)max(cnt, 1);
    uint4 o0, o1;
    o0.x = (uint)f2bf((a[0]+b[0]) * inv)   | ((uint)f2bf((a[1]+b[1]) * inv)   << 16);
    o0.y = (uint)f2bf((a[2]+b[2]) * inv)   | ((uint)f2bf((a[3]+b[3]) * inv)   << 16);
    o0.z = (uint)f2bf((a[4]+b[4]) * inv)   | ((uint)f2bf((a[5]+b[5]) * inv)   << 16);
    o0.w = (uint)f2bf((a[6]+b[6]) * inv)   | ((uint)f2bf((a[7]+b[7]) * inv)   << 16);
    o1.x = (uint)f2bf((a[8]+b[8]) * inv)   | ((uint)f2bf((a[9]+b[9]) * inv)   << 16);
    o1.y = (uint)f2bf((a[10]+b[10]) * inv) | ((uint)f2bf((a[11]+b[11]) * inv) << 16);
    o1.z = (uint)f2bf((a[12]+b[12]) * inv) | ((uint)f2bf((a[13]+b[13]) * inv) << 16);
    o1.w = (uint)f2bf((a[14]+b[14]) * inv) | ((uint)f2bf((a[15]+b[15]) * inv) << 16);
    ushort* o = agg + (size_t)wid * 1024 + g * 128 + (j << 4);
    reinterpret_cast<uint4*>(o)[0] = o0;
    reinterpret_cast<uint4*>(o)[1] = o1;
}

// ---------------- MFMA GEMM: h = relu(bias + [xb|agg] @ Bt^T) ----------------
// A logical [N, 1152] bf16 (xb cols 0..127, agg cols 128..1151), Bt [128][1152] bf16.
// Block: 256 thr = 4 waves (2x2), tile 64(M) x 128(N), BK=64, mfma 32x32x16.
// Double-buffered LDS 48KB; gload_lds linear dest, swizzle on source+read.
__global__ __launch_bounds__(256) void gemm_mfma(const ushort* __restrict__ xb,
                                                 const ushort* __restrict__ agg,
                                                 const ushort* __restrict__ Bt,
                                                 const float* __restrict__ bias,
                                                 ushort* __restrict__ hout) {
    __shared__ __align__(16) uint8_t smem[49152];
    const int t = threadIdx.x;
    const int lane = t & 63;
    const int w = t >> 6;
    const int wr = w >> 1, wc = w & 1;
    const int n0 = blockIdx.x * 64;
    const int l31 = lane & 31;
    const int lhalf = lane >> 5;

    f32x16 acc0, acc1;
#pragma unroll
    for (int r = 0; r < 16; ++r) { acc0[r] = 0.f; acc1[r] = 0.f; }

    const int rA = wr * 32 + l31;
    const int aoff = rA * 128, aswz = (rA & 7) << 4;
    const int nB0 = wc * 64 + l31;
    const int nB1 = nB0 + 32;
    const int boff0 = 8192 + nB0 * 128, bswz0 = (nB0 & 7) << 4;
    const int boff1 = 8192 + nB1 * 128, bswz1 = (nB1 & 7) << 4;
    const int ckb = lhalf << 4;

    const int rsub = lane >> 3;
    const int srcChunk = (((lane & 7) ^ (lane >> 3)) << 4);
    int garowA[2];
#pragma unroll
    for (int jj = 0; jj < 2; ++jj)
        garowA[jj] = min(n0 + 16 * w + 8 * jj + rsub, NN - 1);
    size_t bOffG[4];
#pragma unroll
    for (int jj = 0; jj < 4; ++jj)
        bOffG[jj] = (size_t)(32 * w + 8 * jj + rsub) * 2304 + srcChunk;

    const uint8_t* xb8  = (const uint8_t*)xb;
    const uint8_t* agg8 = (const uint8_t*)agg;
    const uint8_t* Bt8  = (const uint8_t*)Bt;

    auto STAGE = [&](int buf, int kt) {
        uint8_t* base = smem + buf * 24576;
        const uint8_t* Asrc; int shift, koffB;
        if (kt < 2) { Asrc = xb8;  shift = 8;  koffB = kt * 128; }
        else        { Asrc = agg8; shift = 11; koffB = (kt - 2) * 128; }
#pragma unroll
        for (int jj = 0; jj < 2; ++jj)
            stage16(Asrc + (((size_t)garowA[jj]) << shift) + koffB + srcChunk,
                    base + (2 * w + jj) * 1024);
#pragma unroll
        for (int jj = 0; jj < 4; ++jj)
            stage16(Bt8 + bOffG[jj] + kt * 128,
                    base + 8192 + (4 * w + jj) * 1024);
    };

    auto COMPUTE = [&](int buf) {
        const uint8_t* base = smem + buf * 24576;
#pragma unroll
        for (int kb = 0; kb < 4; ++kb) {
            const int cb = kb * 32 + ckb;
            const bf16x8 af = *reinterpret_cast<const bf16x8*>(base + aoff  + (cb ^ aswz));
            const bf16x8 b0 = *reinterpret_cast<const bf16x8*>(base + boff0 + (cb ^ bswz0));
            const bf16x8 b1 = *reinterpret_cast<const bf16x8*>(base + boff1 + (cb ^ bswz1));
            acc0 = __builtin_amdgcn_mfma_f32_32x32x16_bf16(af, b0, acc0, 0, 0, 0);
            acc1 = __builtin_amdgcn_mfma_f32_32x32x16_bf16(af, b1, acc1, 0, 0, 0);
        }
    };

    STAGE(0, 0);
    __syncthreads();
    int cur = 0;
#pragma unroll 1
    for (int kt = 0; kt < 17; ++kt) {
        STAGE(cur ^ 1, kt + 1);
        COMPUTE(cur);
        __syncthreads();
        cur ^= 1;
    }
    COMPUTE(cur);

#pragma unroll
    for (int ni = 0; ni < 2; ++ni) {
        const int col = wc * 64 + ni * 32 + l31;
        const float bv = bias[col];
        const f32x16& a = ni ? acc1 : acc0;
#pragma unroll
        for (int reg = 0; reg < 16; ++reg) {
            const int row = n0 + wr * 32 + 4 * lhalf + (reg & 3) + 8 * (reg >> 2);
            if (row < NN) {
                const float v = fmaxf(a[reg] + bv, 0.f);
                hout[(size_t)row * 128 + col] = f2bf(v);
            }
        }
    }
}

// ---------------- head: out[n] = h2[n] . Wout + bout ----------------
__global__ __launch_bounds__(256) void out_kernel(const ushort* __restrict__ h2,
                                                  const float* __restrict__ Wout,
                                                  const float* __restrict__ bout,
                                                  float* __restrict__ outp) {
    const int wid = (blockIdx.x * blockDim.x + threadIdx.x) >> 6;
    if (wid >= NN) return;
    const int lane = threadIdx.x & 63;
    const uint v = *reinterpret_cast<const uint*>(h2 + (size_t)wid * 128 + (lane << 1));
    const float2 ww = *reinterpret_cast<const float2*>(Wout + (lane << 1));
    float s = fmaf(bflo(v), ww.x, bfhi(v) * ww.y);
#pragma unroll
    for (int d = 32; d > 0; d >>= 1) s += __shfl_down(s, d, 64);
    if (lane == 0) outp[wid] = s + bout[0];
}

extern "C" void kernel_launch(void* const* d_in, const int* in_sizes, int n_in,
                              void* d_out, int out_size, void* d_ws, size_t ws_size,
                              hipStream_t stream) {
    const float* x     = (const float*)d_in[0];
    const int*   eidx  = (const int*)  d_in[1];
    const int*   etype = (const int*)  d_in[2];
    const float* W1    = (const float*)d_in[3];
    const float* root1 = (const float*)d_in[4];
    const float* b1    = (const float*)d_in[5];
    const float* W2    = (const float*)d_in[6];
    const float* root2 = (const float*)d_in[7];
    const float* b2    = (const float*)d_in[8];
    const float* Wout  = (const float*)d_in[9];
    const float* bout  = (const float*)d_in[10];
    float* out = (float*)d_out;

    const int* src = eidx;
    const int* dst = eidx + EE;

    char* ws = (char*)d_ws;
    size_t pos = 0;
    auto take = [&](size_t bytes) {
        char* p = ws + pos;
        pos = (pos + bytes + 255) & ~(size_t)255;
        return p;
    };
    int*    ghist  = (int*)   take((size_t)NCB * 4);
    int*    gstart = (int*)   take((size_t)(NCB + 1) * 4);
    int*    gcur   = (int*)   take((size_t)NCB * 4);
    uint*   packed = (uint*)  take((size_t)EE * 4);
    int*    off    = (int*)   take((size_t)(NB + 1) * 4);
    int*    srcs   = (int*)   take((size_t)EE * 4);
    ushort* xb     = (ushort*)take((size_t)NN * 128 * 2);
    ushort* h1     = (ushort*)take((size_t)NN * 128 * 2);
    ushort* h2     = (ushort*)take((size_t)NN * 128 * 2);
    ushort* agg    = (ushort*)take((size_t)NN * 1024 * 2);
    ushort* Bt1    = (ushort*)take((size_t)128 * 1152 * 2);
    ushort* Bt2    = (ushort*)take((size_t)128 * 1152 * 2);
    (void)ws_size; (void)n_in; (void)in_sizes; (void)out_size;

    const int wblocks = (NN + 3) / 4;               // 12500 wave-per-node
    const int gblocks = (NN + 63) / 64;             // 782 GEMM tiles

    hipMemsetAsync(ghist, 0, (size_t)NCB * 4, stream);
    chist_kernel<<<PBLK, 1024, 0, stream>>>(dst, ghist);
    cscan_kernel<<<1, 256, 0, stream>>>(ghist, gstart, gcur);
    cpart_kernel<<<PBLK, 1024, 0, stream>>>(src, dst, etype, gcur, packed);
    fsort_kernel<<<NCB, 1024, 0, stream>>>(gstart, packed, off, srcs);
    prep_w_kernel<<<dim3(128, 2), 256, 0, stream>>>(root1, W1, root2, W2, Bt1, Bt2);
    cvt_x_kernel <<<3125, 256, 0, stream>>>(x, xb);

    // layer 1
    agg_kernel<<<wblocks, 256, 0, stream>>>(off, srcs, xb, agg);
    gemm_mfma <<<gblocks, 256, 0, stream>>>(xb, agg, Bt1, b1, h1);
    // layer 2
    agg_kernel<<<wblocks, 256, 0, stream>>>(off, srcs, h1, agg);
    gemm_mfma <<<gblocks, 256, 0, stream>>>(h1, agg, Bt2, b2, h2);
    // head
    out_kernel<<<wblocks, 256, 0, stream>>>(h2, Wout, bout, out);
}